// Round 3
// baseline (174.965 us; speedup 1.0000x reference)
//
#include <hip/hip_runtime.h>

// LinearAttention: out[b,n,v] = sum_k q[b,k,n] * ktv[b,k,v],
//                  ktv[b,k,v] = sum_n K[b,n,k] * V[b,n,v]
// B=16, DK=64, N=8192, DV=64, fp32.
//
// R2: same as R1 (8x8 register tiles, register-pipelined staging in p1,
// in-block cross-wave reduction) with the LDS pointer-array removed
// (addrspace(3) static-initializer doesn't compile on gfx950) — buffer
// selection now via index arithmetic.

#define B_      16
#define N_      8192
#define DK_     64
#define DV_     64
#define CHUNKS_ 32
#define ROWS_   256   // rows per chunk
#define SUB_    4     // 64-row subtiles per chunk

// ---------------- Phase 1: partial K^T V per (chunk, batch) ----------------
// grid (32, 16), 256 threads (4 waves). Block output: one 64x64 partial.
// Wave w accumulates rows [w*16, w*16+16) of each 64-row subtile with an
// 8x8 per-lane register tile; 4 wave-partials reduced through LDS at the end.
__global__ __launch_bounds__(256) void p1_partial(
    const float* __restrict__ K, const float* __restrict__ V,
    float* __restrict__ part)
{
    __shared__ float sm[4][4096];   // 64 KB: [0]=K buf0 [1]=V buf0 [2]=K buf1 [3]=V buf1
                                    // epilogue: 4 per-wave partial regions

    const int c = blockIdx.x, b = blockIdx.y, t = threadIdx.x;
    const int w = t >> 6, lane = t & 63;
    const int kk = (lane >> 3) * 8;   // 8 k-groups
    const int vv = (lane & 7) * 8;    // 8 v-groups

    const float4* K4 = (const float4*)(K + ((size_t)b * N_ + (size_t)c * ROWS_) * DK_);
    const float4* V4 = (const float4*)(V + ((size_t)b * N_ + (size_t)c * ROWS_) * DV_);
    // subtile s = K4 + s*1024 (64 rows x 16 float4)

    // prologue: stage subtile 0 into buffers sm[0] (K) and sm[1] (V)
    #pragma unroll
    for (int j = 0; j < 4; ++j) {
        ((float4*)sm[0])[t + 256 * j] = K4[t + 256 * j];
        ((float4*)sm[1])[t + 256 * j] = V4[t + 256 * j];
    }
    __syncthreads();

    float acc[8][8] = {};

    for (int s = 0; s < SUB_; ++s) {
        float4 nk[4], nv[4];
        if (s + 1 < SUB_) {               // issue next-subtile loads early
            const float4* Kn = K4 + (size_t)(s + 1) * 1024;
            const float4* Vn = V4 + (size_t)(s + 1) * 1024;
            #pragma unroll
            for (int j = 0; j < 4; ++j) {
                nk[j] = Kn[t + 256 * j];
                nv[j] = Vn[t + 256 * j];
            }
        }

        const float* cK = sm[(s & 1) * 2];
        const float* cV = sm[(s & 1) * 2 + 1];
        #pragma unroll
        for (int rr = 0; rr < 16; ++rr) {
            const int r = w * 16 + rr;
            alignas(16) float fk[8], fv[8];
            *(float4*)&fk[0] = *(const float4*)&cK[r * 64 + kk];
            *(float4*)&fk[4] = *(const float4*)&cK[r * 64 + kk + 4];
            *(float4*)&fv[0] = *(const float4*)&cV[r * 64 + vv];
            *(float4*)&fv[4] = *(const float4*)&cV[r * 64 + vv + 4];
            #pragma unroll
            for (int i = 0; i < 8; ++i)
                #pragma unroll
                for (int j = 0; j < 8; ++j)
                    acc[i][j] += fk[i] * fv[j];
        }

        if (s + 1 < SUB_) {               // drain loads into the other buffer
            float* wK = sm[((s + 1) & 1) * 2];
            float* wV = sm[((s + 1) & 1) * 2 + 1];
            #pragma unroll
            for (int j = 0; j < 4; ++j) {
                ((float4*)wK)[t + 256 * j] = nk[j];
                ((float4*)wV)[t + 256 * j] = nv[j];
            }
        }
        __syncthreads();
    }

    // cross-wave reduction: wave w dumps its 8x8 tile into region sm[w]
    float* reg = sm[w];
    #pragma unroll
    for (int i = 0; i < 8; ++i) {
        *(float4*)&reg[(kk + i) * 64 + vv]     = make_float4(acc[i][0], acc[i][1], acc[i][2], acc[i][3]);
        *(float4*)&reg[(kk + i) * 64 + vv + 4] = make_float4(acc[i][4], acc[i][5], acc[i][6], acc[i][7]);
    }
    __syncthreads();

    float4* P = (float4*)(part + ((size_t)c * B_ + b) * 4096);
    #pragma unroll
    for (int j = 0; j < 4; ++j) {
        const int idx = t + 256 * j;      // < 1024
        const float4 s0 = ((const float4*)sm[0])[idx];
        const float4 s1 = ((const float4*)sm[1])[idx];
        const float4 s2 = ((const float4*)sm[2])[idx];
        const float4 s3 = ((const float4*)sm[3])[idx];
        P[idx] = make_float4(s0.x + s1.x + s2.x + s3.x,
                             s0.y + s1.y + s2.y + s3.y,
                             s0.z + s1.z + s2.z + s3.z,
                             s0.w + s1.w + s2.w + s3.w);
    }
}

// ---------------- Phase 1b: reduce 32 partials -> ktv ----------------
// grid 64 x 256; 16384 float4 outputs. 32 unrolled independent loads/thread.
__global__ __launch_bounds__(256) void p1_reduce(
    const float* __restrict__ part, float* __restrict__ ktv)
{
    const int i = blockIdx.x * 256 + threadIdx.x;   // float4 index, < 16384
    float4 s = make_float4(0.f, 0.f, 0.f, 0.f);
    #pragma unroll
    for (int c = 0; c < CHUNKS_; ++c) {
        const float4 p = ((const float4*)part)[(size_t)c * 16384 + i];
        s.x += p.x; s.y += p.y; s.z += p.z; s.w += p.w;
    }
    ((float4*)ktv)[i] = s;
}

// ---------------- Phase 2: out = q^T ktv ----------------
// grid (32, 16), 256 threads. Block tile 256n x 64v, thread tile 8n x 8v.
// LDS: qs 64 KB + ks 16 KB = 80 KB -> 2 blocks/CU (gfx950: 160 KB/WG ok).
__global__ __launch_bounds__(256) void p2(
    const float* __restrict__ q, const float* __restrict__ ktv,
    float* __restrict__ out)
{
    __shared__ float qs[64 * 256];   // [k][n_local]
    __shared__ float ks[64 * 64];    // [k][v]

    const int nb = blockIdx.x, b = blockIdx.y, t = threadIdx.x;
    const int n0 = nb * 256;
    const int nl = (t >> 3) * 8;     // 32 n-groups
    const int vl = (t & 7) * 8;      // 8 v-groups

    const float4* kt4 = (const float4*)(ktv + (size_t)b * 4096);
    #pragma unroll
    for (int j = 0; j < 4; ++j)
        ((float4*)ks)[t + 256 * j] = kt4[t + 256 * j];

    const float* qb = q + (size_t)b * DK_ * N_ + n0;
    #pragma unroll
    for (int j = 0; j < 16; ++j) {
        const int i  = t + 256 * j;  // < 4096
        const int k  = i >> 6;       // 64 float4 per 256-float row
        const int c4 = i & 63;
        ((float4*)&qs[k * 256])[c4] = ((const float4*)&qb[(size_t)k * N_])[c4];
    }
    __syncthreads();

    float acc[8][8] = {};
    #pragma unroll 4
    for (int k = 0; k < 64; ++k) {
        alignas(16) float qn[8], kv[8];
        *(float4*)&qn[0] = *(const float4*)&qs[k * 256 + nl];
        *(float4*)&qn[4] = *(const float4*)&qs[k * 256 + nl + 4];
        *(float4*)&kv[0] = *(const float4*)&ks[k * 64 + vl];
        *(float4*)&kv[4] = *(const float4*)&ks[k * 64 + vl + 4];
        #pragma unroll
        for (int i = 0; i < 8; ++i)
            #pragma unroll
            for (int j = 0; j < 8; ++j)
                acc[i][j] += qn[i] * kv[j];
    }

    float* ob = out + ((size_t)b * N_ + n0 + nl) * DV_ + vl;
    #pragma unroll
    for (int i = 0; i < 8; ++i) {
        *(float4*)&ob[(size_t)i * DV_]     = make_float4(acc[i][0], acc[i][1], acc[i][2], acc[i][3]);
        *(float4*)&ob[(size_t)i * DV_ + 4] = make_float4(acc[i][4], acc[i][5], acc[i][6], acc[i][7]);
    }
}

extern "C" void kernel_launch(void* const* d_in, const int* in_sizes, int n_in,
                              void* d_out, int out_size, void* d_ws, size_t ws_size,
                              hipStream_t stream)
{
    (void)in_sizes; (void)n_in; (void)out_size; (void)ws_size;
    const float* q = (const float*)d_in[0];   // [16, 64, 8192]
    const float* k = (const float*)d_in[1];   // [16, 8192, 64]
    const float* v = (const float*)d_in[2];   // [16, 8192, 64]
    float* out = (float*)d_out;               // [16, 8192, 64]

    // ws: [32][16][4096] partials (8 MB) + [16][4096] ktv (256 KB)
    float* part = (float*)d_ws;
    float* ktv  = part + (size_t)CHUNKS_ * B_ * 4096;

    p1_partial<<<dim3(CHUNKS_, B_), 256, 0, stream>>>(k, v, part);
    p1_reduce<<<dim3(64), 256, 0, stream>>>(part, ktv);
    p2<<<dim3(32, B_), 256, 0, stream>>>(q, ktv, out);
}

// Round 4
// 151.682 us; speedup vs baseline: 1.1535x; 1.1535x over previous
//
#include <hip/hip_runtime.h>

// LinearAttention: out[b,n,v] = sum_k q[b,k,n] * ktv[b,k,v],
//                  ktv[b,k,v] = sum_n K[b,n,k] * V[b,n,v]
// B=16, DK=64, N=8192, DV=64, fp32.
//
// R4: occupancy-first rewrite after R3 post-mortem (Occupancy 10%, VALU 17%).
//  - Wave-independent tiles: each wave owns a private 16 KB LDS region and
//    its own rows -> NO __syncthreads in the hot loop (per-wave DS ordering).
//  - 8x8 register tile kept (4 ds_read_b128 per 64 FMA -> VALU-bound/wave).
//  - No register prefetch (that cost R3 ~50 VGPRs -> 2 waves/SIMD).
//  - p1: 512 blocks, 64 KB LDS -> 2 blocks/CU, 8 waves/CU resident.
//  - reduce: 256 blocks (was 64: quarter-chip).
//  - HBM floors: p1 ~72 MB -> 11.4 us, p2 ~64 MB -> 10.2 us.

#define B_   16
#define N_   8192
#define DK_  64
#define DV_  64
#define CH_  32      // chunks; rows per chunk = 256 (64 per wave, 2 rounds of 32)

// ---------------- Phase 1: partial K^T V ----------------
// grid (32, 16), 256 threads (4 waves). Wave w: rows [w*64, w*64+64) of the
// chunk, 2 staging rounds of 32 rows in its private 16 KB region. Epilogue:
// one barrier, cross-wave sum of 4 wave partials, one 16 KB global write.
__global__ __launch_bounds__(256) void p1_partial(
    const float* __restrict__ K, const float* __restrict__ V,
    float* __restrict__ part)
{
    __shared__ float sm[4][4096];   // 64 KB; wave-private: [0..2047]=K, [2048..4095]=V

    const int c = blockIdx.x, b = blockIdx.y, t = threadIdx.x;
    const int w = t >> 6, lane = t & 63;
    const int kk = (lane >> 3) * 8;   // 8 k-groups of 8
    const int vv = (lane & 7) * 8;    // 8 v-groups of 8

    float* Ks = &sm[w][0];
    float* Vs = &sm[w][2048];

    const size_t row0 = (size_t)b * N_ + (size_t)c * 256 + (size_t)w * 64;
    const float4* K4 = (const float4*)(K + row0 * DK_);   // 16 float4 per row
    const float4* V4 = (const float4*)(V + row0 * DV_);

    float acc[8][8] = {};

    for (int r = 0; r < 2; ++r) {
        // stage 32 rows of K and V (8+8 x 16B per lane, 4 full rows per instr)
        #pragma unroll
        for (int j = 0; j < 8; ++j) {
            ((float4*)Ks)[lane + 64 * j] = K4[r * 512 + lane + 64 * j];
            ((float4*)Vs)[lane + 64 * j] = V4[r * 512 + lane + 64 * j];
        }
        // wave-private region: no barrier; compiler waitcnts cover vm->ds->use
        #pragma unroll 4
        for (int n = 0; n < 32; ++n) {
            alignas(16) float fk[8], fv[8];
            *(float4*)&fk[0] = *(const float4*)&Ks[n * 64 + kk];
            *(float4*)&fk[4] = *(const float4*)&Ks[n * 64 + kk + 4];
            *(float4*)&fv[0] = *(const float4*)&Vs[n * 64 + vv];
            *(float4*)&fv[4] = *(const float4*)&Vs[n * 64 + vv + 4];
            #pragma unroll
            for (int i = 0; i < 8; ++i)
                #pragma unroll
                for (int j = 0; j < 8; ++j)
                    acc[i][j] += fk[i] * fv[j];
        }
    }

    // dump wave partial into own region (own reads are done; wave-coherent)
    float* reg = sm[w];
    #pragma unroll
    for (int i = 0; i < 8; ++i) {
        *(float4*)&reg[(kk + i) * 64 + vv]     = make_float4(acc[i][0], acc[i][1], acc[i][2], acc[i][3]);
        *(float4*)&reg[(kk + i) * 64 + vv + 4] = make_float4(acc[i][4], acc[i][5], acc[i][6], acc[i][7]);
    }
    __syncthreads();

    float4* P = (float4*)(part + ((size_t)c * B_ + b) * 4096);
    #pragma unroll
    for (int j = 0; j < 4; ++j) {
        const int idx = t + 256 * j;      // < 1024
        const float4 s0 = ((const float4*)sm[0])[idx];
        const float4 s1 = ((const float4*)sm[1])[idx];
        const float4 s2 = ((const float4*)sm[2])[idx];
        const float4 s3 = ((const float4*)sm[3])[idx];
        P[idx] = make_float4(s0.x + s1.x + s2.x + s3.x,
                             s0.y + s1.y + s2.y + s3.y,
                             s0.z + s1.z + s2.z + s3.z,
                             s0.w + s1.w + s2.w + s3.w);
    }
}

// ---------------- Phase 1b: reduce 32 partials -> ktv ----------------
// grid 256 x 256; one float per thread, coalesced, 32-way unrolled.
__global__ __launch_bounds__(256) void p1_reduce(
    const float* __restrict__ part, float* __restrict__ ktv)
{
    const int idx = blockIdx.x * 256 + threadIdx.x;   // [0, 65536)
    float s = 0.f;
    #pragma unroll
    for (int c = 0; c < CH_; ++c)
        s += part[(size_t)c * 65536 + idx];
    ktv[idx] = s;
}

// ---------------- Phase 2: out = q^T ktv ----------------
// grid (32, 16), 256 threads (4 waves). Wave w: 64 n-rows at nb*256+w*64,
// private 16 KB q tile; ktv[b] staged once in shared 16 KB. One barrier.
__global__ __launch_bounds__(256) void p2(
    const float* __restrict__ q, const float* __restrict__ ktv,
    float* __restrict__ out)
{
    __shared__ float ks[4096];       // 16 KB: ktv[b], [k][v]
    __shared__ float qs[4][4096];    // 64 KB: wave-private, [k][64 n]

    const int nb = blockIdx.x, b = blockIdx.y, t = threadIdx.x;
    const int w = t >> 6, lane = t & 63;
    const int nl = (lane >> 3) * 8;  // 8 n-groups of 8
    const int vl = (lane & 7) * 8;   // 8 v-groups of 8
    const int n0 = nb * 256 + w * 64;

    // stage ktv[b] cooperatively
    const float4* kt4 = (const float4*)(ktv + (size_t)b * 4096);
    #pragma unroll
    for (int j = 0; j < 4; ++j)
        ((float4*)ks)[t + 256 * j] = kt4[t + 256 * j];

    // stage q tile: q[b][k][n0..n0+64], k=0..63 -> qs[w][k*64 + col]
    const float* qb = q + (size_t)b * DK_ * N_ + n0;
    #pragma unroll
    for (int j = 0; j < 16; ++j) {
        const int idx = lane + 64 * j;   // [0, 1024) float4 units; k=idx>>4, c4=idx&15
        ((float4*)qs[w])[idx] =
            ((const float4*)(qb + (size_t)(idx >> 4) * N_))[idx & 15];
    }
    __syncthreads();

    float acc[8][8] = {};
    #pragma unroll 8
    for (int k = 0; k < 64; ++k) {
        alignas(16) float fq[8], fv[8];
        *(float4*)&fq[0] = *(const float4*)&qs[w][k * 64 + nl];
        *(float4*)&fq[4] = *(const float4*)&qs[w][k * 64 + nl + 4];
        *(float4*)&fv[0] = *(const float4*)&ks[k * 64 + vl];
        *(float4*)&fv[4] = *(const float4*)&ks[k * 64 + vl + 4];
        #pragma unroll
        for (int i = 0; i < 8; ++i)
            #pragma unroll
            for (int j = 0; j < 8; ++j)
                acc[i][j] += fq[i] * fv[j];
    }

    // out[b][n0+nl+i][vl..vl+8]: 8 lanes per group write 256 B contiguous
    float* ob = out + ((size_t)b * N_ + n0 + nl) * DV_ + vl;
    #pragma unroll
    for (int i = 0; i < 8; ++i) {
        *(float4*)&ob[(size_t)i * DV_]     = make_float4(acc[i][0], acc[i][1], acc[i][2], acc[i][3]);
        *(float4*)&ob[(size_t)i * DV_ + 4] = make_float4(acc[i][4], acc[i][5], acc[i][6], acc[i][7]);
    }
}

extern "C" void kernel_launch(void* const* d_in, const int* in_sizes, int n_in,
                              void* d_out, int out_size, void* d_ws, size_t ws_size,
                              hipStream_t stream)
{
    (void)in_sizes; (void)n_in; (void)out_size; (void)ws_size;
    const float* q = (const float*)d_in[0];   // [16, 64, 8192]
    const float* k = (const float*)d_in[1];   // [16, 8192, 64]
    const float* v = (const float*)d_in[2];   // [16, 8192, 64]
    float* out = (float*)d_out;               // [16, 8192, 64]

    // ws: [32][16][4096] partials (8 MB) + [16][4096] ktv (256 KB)
    float* part = (float*)d_ws;
    float* ktv  = part + (size_t)CH_ * B_ * 4096;

    p1_partial<<<dim3(CH_, B_), 256, 0, stream>>>(k, v, part);
    p1_reduce<<<dim3(256), 256, 0, stream>>>(part, ktv);
    p2<<<dim3(32, B_), 256, 0, stream>>>(q, ktv, out);
}